// Round 4
// baseline (188.359 us; speedup 1.0000x reference)
//
#include <hip/hip_runtime.h>
#include <hip/hip_cooperative_groups.h>
#include <math.h>

namespace cgx = cooperative_groups;

// Quantized softmax over axis 1 of x(8, 4096, 1024) fp32.
// Groups: g = (b, c) column, 8192 groups of 4096 elements (stride 1024 floats).
//
// FUSED single-kernel design (cooperative launch, 256 blocks x 1024 thr):
//   Each block owns a (b, 32-column) slab = 32 full groups. All 4096x32 int8
//   codes live in registers (32 x c4 per thread). Only 3 GLOBAL scalars
//   (amax_sub, max_s, min_s) cross blocks -> per-block values in ws +
//   2 grid syncs + per-block re-reduction (atomic-free, deterministic).
// Traffic: read x once (128 MiB) + write out once (128 MiB) + ~3 KB.
// Fallback (if coop launch fails): proven round-3 5-kernel path.

typedef float       f4 __attribute__((ext_vector_type(4)));
typedef signed char c4 __attribute__((ext_vector_type(4)));

static constexpr int Bdim = 8;
static constexpr int Jdim = 4096;
static constexpr int Cdim = 1024;

// ---- fused geometry ----
static constexpr int CT    = 32;            // columns per block (128 B/row segment)
static constexpr int NCT   = Cdim / CT;     // 32
static constexpr int FGRID = Bdim * NCT;    // 256 blocks = 1 per CU
static constexpr int FBLK  = 1024;          // 16 waves
static constexpr int KROWS = 32;            // rows per thread
static constexpr int RSTEP = 128;           // row stride between k iterations

__device__ __forceinline__ float code8f(float x, float sinv) {
    // int8 code as float; rintf = round-half-even matches jnp.round
    return fminf(fmaxf(rintf(x * sinv), -128.0f), 127.0f);
}
// e_q = fq16(exp(fq16(clip(xq - gmax, -12, 0)))); scale_e = 1/32767 exactly
// (group-max element has sub==0 -> e==1 -> absmax(e)==1).
__device__ __forceinline__ float eq_from(float xq, float gmv, float ssub_inv, float ssub) {
    float sub = fminf(fmaxf(xq - gmv, -12.0f), 0.0f);
    float q   = rintf(sub * ssub_inv);
    float e   = __expf(q * ssub);
    return rintf(e * 32767.0f) * (1.0f / 32767.0f);
}

__device__ __forceinline__ f4 shfl_xor4(f4 v, int off) {
    f4 r; r[0] = __shfl_xor(v[0], off); r[1] = __shfl_xor(v[1], off);
    r[2] = __shfl_xor(v[2], off); r[3] = __shfl_xor(v[3], off); return r;
}
__device__ __forceinline__ f4 fmax4v(f4 a, f4 b) {
    f4 r; r[0]=fmaxf(a[0],b[0]); r[1]=fmaxf(a[1],b[1]);
    r[2]=fmaxf(a[2],b[2]); r[3]=fmaxf(a[3],b[3]); return r;
}
__device__ __forceinline__ f4 fmin4v(f4 a, f4 b) {
    f4 r; r[0]=fminf(a[0],b[0]); r[1]=fminf(a[1],b[1]);
    r[2]=fminf(a[2],b[2]); r[3]=fminf(a[3],b[3]); return r;
}
__device__ __forceinline__ f4 add4v(f4 a, f4 b) {
    f4 r; r[0]=a[0]+b[0]; r[1]=a[1]+b[1]; r[2]=a[2]+b[2]; r[3]=a[3]+b[3]; return r;
}

__global__ __launch_bounds__(FBLK, 4) void k_fused(const float* __restrict__ x,
                                                   const float* __restrict__ scale,
                                                   float* __restrict__ out,
                                                   float* __restrict__ wsf) {
    const int bid   = blockIdx.x;
    const int b     = bid / NCT;
    const int ctile = bid % NCT;
    const int t     = threadIdx.x;
    const int cgp   = t & 7;       // col group: 4 cols
    const int rg    = t >> 3;      // 0..127 row group
    const int w     = t >> 6;      // wave 0..15
    const int l     = t & 63;      // lane
    const float s    = scale[0];
    const float sinv = 1.0f / s;

    float* dblk  = wsf;            // [256] per-block max |clip(sub)|
    float* smaxb = wsf + 256;      // [256] per-block max group-sum
    float* sminb = wsf + 512;      // [256] per-block min group-sum

    __shared__ f4 lA[16][8], lB[16][8];
    __shared__ f4 gmaxs[8];        // per-colgroup max codes (block scope)
    __shared__ f4 scol[8];         // per-colgroup group sums
    __shared__ float bc[3];

    const size_t base = ((size_t)b * Jdim + rg) * Cdim + (size_t)(ctile * CT + cgp * 4);

    // ---------- Phase A: read x, quantize -> regs, per-col max/min ----------
    c4 codes[KROWS];
    f4 vmax = {-1e30f, -1e30f, -1e30f, -1e30f};
    f4 vmin = { 1e30f,  1e30f,  1e30f,  1e30f};
#pragma unroll
    for (int k = 0; k < KROWS; ++k) {
        const f4 v = __builtin_nontemporal_load(
            reinterpret_cast<const f4*>(x + base + (size_t)k * RSTEP * Cdim));
        f4 q;
        q[0] = code8f(v[0], sinv); q[1] = code8f(v[1], sinv);
        q[2] = code8f(v[2], sinv); q[3] = code8f(v[3], sinv);
        vmax = fmax4v(vmax, q); vmin = fmin4v(vmin, q);
        codes[k] = (c4){(signed char)(int)q[0], (signed char)(int)q[1],
                        (signed char)(int)q[2], (signed char)(int)q[3]};
    }
    // intra-wave reduce over rg bits (lanes 8,16,32 apart share col group)
#pragma unroll
    for (int off = 8; off < 64; off <<= 1) {
        vmax = fmax4v(vmax, shfl_xor4(vmax, off));
        vmin = fmin4v(vmin, shfl_xor4(vmin, off));
    }
    if (l < 8) { lA[w][l] = vmax; lB[w][l] = vmin; }
    __syncthreads();
    if (w == 0) {
        const int wcg = l & 7, wi = l >> 3;         // wi 0..7
        f4 m = fmax4v(lA[wi][wcg], lA[wi + 8][wcg]);
        f4 n = fmin4v(lB[wi][wcg], lB[wi + 8][wcg]);
#pragma unroll
        for (int off = 8; off < 64; off <<= 1) {
            m = fmax4v(m, shfl_xor4(m, off));
            n = fmin4v(n, shfl_xor4(n, off));
        }
        if (l < 8) gmaxs[l] = m;                     // codes (as float)
        // d = max over 4 cols of min(12, gmax_v - gmin_v)   (same fp ops as ref)
        float d;
        {
            float d0 = fminf(12.0f, m[0]*s - n[0]*s);
            float d1 = fminf(12.0f, m[1]*s - n[1]*s);
            float d2 = fminf(12.0f, m[2]*s - n[2]*s);
            float d3 = fminf(12.0f, m[3]*s - n[3]*s);
            d = fmaxf(fmaxf(d0, d1), fmaxf(d2, d3));
        }
#pragma unroll
        for (int off = 1; off < 8; off <<= 1) d = fmaxf(d, __shfl_xor(d, off));
        if (l == 0) dblk[bid] = d;
    }
    cgx::this_grid().sync();

    // ---------- Phase B: amax_sub -> ssub; e_q sums per column ----------
    if (w == 0) {
        const f4 dv = *reinterpret_cast<const f4*>(dblk + 4 * l);  // 64 lanes x 4 = 256
        float dm = fmaxf(fmaxf(dv[0], dv[1]), fmaxf(dv[2], dv[3]));
#pragma unroll
        for (int off = 1; off < 64; off <<= 1) dm = fmaxf(dm, __shfl_xor(dm, off));
        if (l == 0) bc[0] = dm;
    }
    __syncthreads();
    const float amax = fmaxf(bc[0], 1e-9f);
    const float ssub = amax / 32767.0f;
    const float ssub_inv = 1.0f / ssub;
    const f4 gmc = gmaxs[cgp];
    const f4 gm  = {gmc[0]*s, gmc[1]*s, gmc[2]*s, gmc[3]*s};

    f4 acc = {0.f, 0.f, 0.f, 0.f};
#pragma unroll
    for (int k = 0; k < KROWS; ++k) {
        const c4 q = codes[k];
        acc[0] += eq_from((float)q[0]*s, gm[0], ssub_inv, ssub);
        acc[1] += eq_from((float)q[1]*s, gm[1], ssub_inv, ssub);
        acc[2] += eq_from((float)q[2]*s, gm[2], ssub_inv, ssub);
        acc[3] += eq_from((float)q[3]*s, gm[3], ssub_inv, ssub);
    }
#pragma unroll
    for (int off = 8; off < 64; off <<= 1) acc = add4v(acc, shfl_xor4(acc, off));
    if (l < 8) lA[w][l] = acc;                       // reuse lA (phase-A reads done)
    __syncthreads();
    if (w == 0) {
        const int wcg = l & 7, wi = l >> 3;
        f4 tsum = add4v(lA[wi][wcg], lA[wi + 8][wcg]);
#pragma unroll
        for (int off = 8; off < 64; off <<= 1) tsum = add4v(tsum, shfl_xor4(tsum, off));
        if (l < 8) scol[l] = tsum;
        float mx = fmaxf(fmaxf(tsum[0], tsum[1]), fmaxf(tsum[2], tsum[3]));
        float mn = fminf(fminf(tsum[0], tsum[1]), fminf(tsum[2], tsum[3]));
#pragma unroll
        for (int off = 1; off < 8; off <<= 1) {
            mx = fmaxf(mx, __shfl_xor(mx, off));
            mn = fminf(mn, __shfl_xor(mn, off));
        }
        if (l == 0) { smaxb[bid] = mx; sminb[bid] = mn; }
    }
    cgx::this_grid().sync();

    // ---------- Phase C: derive scales; out = fq8(e_q * r_q) ----------
    if (w == 0) {
        const f4 mv = *reinterpret_cast<const f4*>(smaxb + 4 * l);
        const f4 nv = *reinterpret_cast<const f4*>(sminb + 4 * l);
        float mx = fmaxf(fmaxf(mv[0], mv[1]), fmaxf(mv[2], mv[3]));
        float mn = fminf(fminf(nv[0], nv[1]), fminf(nv[2], nv[3]));
#pragma unroll
        for (int off = 1; off < 64; off <<= 1) {
            mx = fmaxf(mx, __shfl_xor(mx, off));
            mn = fminf(mn, __shfl_xor(mn, off));
        }
        if (l == 0) { bc[1] = mx; bc[2] = mn; }
    }
    __syncthreads();
    const float max_s = bc[1], min_s = bc[2];
    // fq monotone: min s_q = fq(min s); max r = 1/min s_q; max r_q = fq(max r)
    const float scale_s = fmaxf(max_s, 1e-9f) / 32767.0f;
    const float ss_inv  = 1.0f / scale_s;
    const float minsq   = fminf(fmaxf(rintf(min_s * ss_inv), -32768.0f), 32767.0f) * scale_s;
    const float maxr    = 1.0f / minsq;
    const float scale_r = fmaxf(maxr, 1e-9f) / 32767.0f;
    const float sr_inv  = 1.0f / scale_r;
    const float maxrq   = fminf(fmaxf(rintf(maxr * sr_inv), -32768.0f), 32767.0f) * scale_r;
    const float scale_out = fmaxf(maxrq, 1e-9f) / 127.0f;
    const float so_inv  = 1.0f / scale_out;

    const f4 sc = scol[cgp];
    f4 rq;
#pragma unroll
    for (int i = 0; i < 4; ++i) {
        float qv = fminf(fmaxf(rintf(sc[i] * ss_inv), -32768.0f), 32767.0f) * scale_s;
        rq[i] = fminf(fmaxf(rintf((1.0f / qv) * sr_inv), -32768.0f), 32767.0f) * scale_r;
    }

#pragma unroll
    for (int k = 0; k < KROWS; ++k) {
        const c4 q = codes[k];
        f4 o;
        {
            float e0 = eq_from((float)q[0]*s, gm[0], ssub_inv, ssub) * rq[0];
            float e1 = eq_from((float)q[1]*s, gm[1], ssub_inv, ssub) * rq[1];
            float e2 = eq_from((float)q[2]*s, gm[2], ssub_inv, ssub) * rq[2];
            float e3 = eq_from((float)q[3]*s, gm[3], ssub_inv, ssub) * rq[3];
            o[0] = fminf(fmaxf(rintf(e0 * so_inv), -128.0f), 127.0f) * scale_out;
            o[1] = fminf(fmaxf(rintf(e1 * so_inv), -128.0f), 127.0f) * scale_out;
            o[2] = fminf(fmaxf(rintf(e2 * so_inv), -128.0f), 127.0f) * scale_out;
            o[3] = fminf(fmaxf(rintf(e3 * so_inv), -128.0f), 127.0f) * scale_out;
        }
        __builtin_nontemporal_store(o,
            reinterpret_cast<f4*>(out + base + (size_t)k * RSTEP * Cdim));
    }
}

// ======================= round-3 fallback path =======================
static constexpr int JCHUNK = 16;
static constexpr int NJC = Jdim / JCHUNK;         // 256
static constexpr int NG = Bdim * Cdim;            // 8192
static constexpr int PSIZE = Bdim * NJC * Cdim;   // 2,097,152

static constexpr int SC_OFF   = 0;
static constexpr int GMAX_OFF = 16;
static constexpr int S_OFF    = GMAX_OFF + NG;
static constexpr int PS_OFF   = S_OFF + NG;
static constexpr size_t FB_BYTES    = ((size_t)PS_OFF + PSIZE) * 4;
static constexpr size_t CODES_BYTES = (size_t)Bdim * Jdim * Cdim;
static constexpr size_t P_BYTES     = 2 * (size_t)PSIZE;

template <bool WC>
__global__ __launch_bounds__(256) void k_pass1(const float* __restrict__ x,
                                               const float* __restrict__ scale,
                                               float* __restrict__ fbuf,
                                               signed char* __restrict__ codes,
                                               signed char* __restrict__ pmax,
                                               signed char* __restrict__ pmin) {
    if (blockIdx.x == 0 && threadIdx.x == 0) {
        fbuf[SC_OFF + 0] = 0.0f;
        fbuf[SC_OFF + 1] = 0.0f;
        fbuf[SC_OFF + 2] = __int_as_float(0x7f800000);
    }
    const int b  = blockIdx.x / NJC;
    const int jc = blockIdx.x % NJC;
    const int c0 = threadIdx.x * 4;
    const float sinv = 1.0f / scale[0];
    const size_t base = ((size_t)(b * Jdim + jc * JCHUNK)) * Cdim + c0;

    f4 vmax = {-1e30f, -1e30f, -1e30f, -1e30f};
    f4 vmin = { 1e30f,  1e30f,  1e30f,  1e30f};
    #pragma unroll 4
    for (int r = 0; r < JCHUNK; ++r) {
        const f4 v = __builtin_nontemporal_load(
            reinterpret_cast<const f4*>(x + base + (size_t)r * Cdim));
        f4 q;
        q[0] = code8f(v[0], sinv); q[1] = code8f(v[1], sinv);
        q[2] = code8f(v[2], sinv); q[3] = code8f(v[3], sinv);
        vmax = fmax4v(vmax, q); vmin = fmin4v(vmin, q);
        if (WC) {
            c4 pk = {(signed char)(int)q[0], (signed char)(int)q[1],
                     (signed char)(int)q[2], (signed char)(int)q[3]};
            *reinterpret_cast<c4*>(codes + base + (size_t)r * Cdim) = pk;
        }
    }
    const size_t pidx = ((size_t)(b * NJC + jc)) * Cdim + c0;
    c4 mx = {(signed char)(int)vmax[0], (signed char)(int)vmax[1],
             (signed char)(int)vmax[2], (signed char)(int)vmax[3]};
    c4 mn = {(signed char)(int)vmin[0], (signed char)(int)vmin[1],
             (signed char)(int)vmin[2], (signed char)(int)vmin[3]};
    *reinterpret_cast<c4*>(pmax + pidx) = mx;
    *reinterpret_cast<c4*>(pmin + pidx) = mn;
}

__global__ __launch_bounds__(256) void k_reduce1(const float* __restrict__ scale,
                                                 float* __restrict__ fbuf,
                                                 const signed char* __restrict__ pmax,
                                                 const signed char* __restrict__ pmin) {
    const int b   = blockIdx.x / 32;
    const int ct  = blockIdx.x % 32;
    const int ci  = threadIdx.x & 31;
    const int sub = threadIdx.x >> 5;
    const int c   = ct * 32 + ci;

    int mx = -128, mn = 127;
    for (int jc = sub; jc < NJC; jc += 8) {
        const size_t idx = ((size_t)(b * NJC + jc)) * Cdim + c;
        mx = max(mx, (int)pmax[idx]);
        mn = min(mn, (int)pmin[idx]);
    }
    __shared__ int smx[8][32], smn[8][32];
    smx[sub][ci] = mx; smn[sub][ci] = mn;
    __syncthreads();
    for (int off = 4; off; off >>= 1) {
        if (sub < off) {
            smx[sub][ci] = max(smx[sub][ci], smx[sub + off][ci]);
            smn[sub][ci] = min(smn[sub][ci], smn[sub + off][ci]);
        }
        __syncthreads();
    }
    __shared__ float sd[32];
    if (sub == 0) {
        const float s = scale[0];
        fbuf[GMAX_OFF + b * Cdim + c] = (float)smx[0][ci];
        sd[ci] = fminf(12.0f, (float)smx[0][ci] * s - (float)smn[0][ci] * s);
    }
    __syncthreads();
    if (threadIdx.x == 0) {
        float m = sd[0];
        #pragma unroll
        for (int i = 1; i < 32; ++i) m = fmaxf(m, sd[i]);
        atomicMax(reinterpret_cast<unsigned int*>(fbuf + SC_OFF + 0), __float_as_uint(m));
    }
}

template <bool UC>
__global__ __launch_bounds__(256) void k_pass2(const float* __restrict__ x,
                                               const signed char* __restrict__ codes,
                                               const float* __restrict__ scale,
                                               float* __restrict__ fbuf) {
    const int b  = blockIdx.x / NJC;
    const int jc = blockIdx.x % NJC;
    const int c0 = threadIdx.x * 4;
    const float s = scale[0];
    const float sinv = 1.0f / s;
    const float amax = fmaxf(fbuf[SC_OFF + 0], 1e-9f);
    const float ssub = amax / 32767.0f;
    const float ssub_inv = 1.0f / ssub;
    const f4 gmc = *reinterpret_cast<const f4*>(fbuf + GMAX_OFF + b * Cdim + c0);
    const float gm0 = gmc[0]*s, gm1 = gmc[1]*s, gm2 = gmc[2]*s, gm3 = gmc[3]*s;
    const size_t base = ((size_t)(b * Jdim + jc * JCHUNK)) * Cdim + c0;

    float a0 = 0.f, a1 = 0.f, a2 = 0.f, a3 = 0.f;
    #pragma unroll 4
    for (int r = 0; r < JCHUNK; ++r) {
        float xq0, xq1, xq2, xq3;
        if (UC) {
            const c4 q = *reinterpret_cast<const c4*>(codes + base + (size_t)r * Cdim);
            xq0 = (float)q[0]*s; xq1 = (float)q[1]*s; xq2 = (float)q[2]*s; xq3 = (float)q[3]*s;
        } else {
            const f4 v = *reinterpret_cast<const f4*>(x + base + (size_t)r * Cdim);
            xq0 = code8f(v[0], sinv)*s; xq1 = code8f(v[1], sinv)*s;
            xq2 = code8f(v[2], sinv)*s; xq3 = code8f(v[3], sinv)*s;
        }
        a0 += eq_from(xq0, gm0, ssub_inv, ssub);
        a1 += eq_from(xq1, gm1, ssub_inv, ssub);
        a2 += eq_from(xq2, gm2, ssub_inv, ssub);
        a3 += eq_from(xq3, gm3, ssub_inv, ssub);
    }
    f4 acc = {a0, a1, a2, a3};
    *reinterpret_cast<f4*>(fbuf + PS_OFF + ((size_t)(b * NJC + jc)) * Cdim + c0) = acc;
}

__global__ __launch_bounds__(256) void k_reduce2(float* __restrict__ fbuf) {
    const int b   = blockIdx.x / 32;
    const int ct  = blockIdx.x % 32;
    const int ci  = threadIdx.x & 31;
    const int sub = threadIdx.x >> 5;
    const int c   = ct * 32 + ci;

    float p = 0.0f;
    for (int jc = sub; jc < NJC; jc += 8)
        p += fbuf[PS_OFF + ((size_t)(b * NJC + jc)) * Cdim + c];
    __shared__ float sp[8][32];
    sp[sub][ci] = p;
    __syncthreads();
    for (int off = 4; off; off >>= 1) {
        if (sub < off) sp[sub][ci] += sp[sub + off][ci];
        __syncthreads();
    }
    __shared__ float smx[32], smn[32];
    if (sub == 0) {
        const float t = sp[0][ci];
        fbuf[S_OFF + b * Cdim + c] = t;
        smx[ci] = t; smn[ci] = t;
    }
    __syncthreads();
    if (threadIdx.x == 0) {
        float mx = smx[0], mn = smn[0];
        #pragma unroll
        for (int i = 1; i < 32; ++i) { mx = fmaxf(mx, smx[i]); mn = fminf(mn, smn[i]); }
        atomicMax(reinterpret_cast<unsigned int*>(fbuf + SC_OFF + 1), __float_as_uint(mx));
        atomicMin(reinterpret_cast<unsigned int*>(fbuf + SC_OFF + 2), __float_as_uint(mn));
    }
}

template <bool UC>
__global__ __launch_bounds__(256) void k_pass3(const float* __restrict__ x,
                                               const signed char* __restrict__ codes,
                                               const float* __restrict__ scale,
                                               const float* __restrict__ fbuf,
                                               float* __restrict__ out) {
    const int b  = blockIdx.x / NJC;
    const int jc = blockIdx.x % NJC;
    const int c0 = threadIdx.x * 4;
    const float s = scale[0];
    const float sinv = 1.0f / s;

    const float amax = fmaxf(fbuf[SC_OFF + 0], 1e-9f);
    const float ssub = amax / 32767.0f;
    const float ssub_inv = 1.0f / ssub;

    const float max_s = fbuf[SC_OFF + 1];
    const float min_s = fbuf[SC_OFF + 2];
    const float scale_s = fmaxf(max_s, 1e-9f) / 32767.0f;
    const float ss_inv = 1.0f / scale_s;
    const float minsq = fminf(fmaxf(rintf(min_s * ss_inv), -32768.0f), 32767.0f) * scale_s;
    const float maxr  = 1.0f / minsq;
    const float scale_r = fmaxf(maxr, 1e-9f) / 32767.0f;
    const float sr_inv  = 1.0f / scale_r;
    const float maxrq = fminf(fmaxf(rintf(maxr * sr_inv), -32768.0f), 32767.0f) * scale_r;
    const float scale_out = fmaxf(maxrq, 1e-9f) / 127.0f;
    const float so_inv = 1.0f / scale_out;

    const f4 gmc = *reinterpret_cast<const f4*>(fbuf + GMAX_OFF + b * Cdim + c0);
    const float gm0 = gmc[0]*s, gm1 = gmc[1]*s, gm2 = gmc[2]*s, gm3 = gmc[3]*s;
    const f4 s4 = *reinterpret_cast<const f4*>(fbuf + S_OFF + b * Cdim + c0);

    f4 rq;
    {
        float q0 = fminf(fmaxf(rintf(s4[0] * ss_inv), -32768.0f), 32767.0f) * scale_s;
        float q1 = fminf(fmaxf(rintf(s4[1] * ss_inv), -32768.0f), 32767.0f) * scale_s;
        float q2 = fminf(fmaxf(rintf(s4[2] * ss_inv), -32768.0f), 32767.0f) * scale_s;
        float q3 = fminf(fmaxf(rintf(s4[3] * ss_inv), -32768.0f), 32767.0f) * scale_s;
        rq[0] = fminf(fmaxf(rintf((1.0f/q0) * sr_inv), -32768.0f), 32767.0f) * scale_r;
        rq[1] = fminf(fmaxf(rintf((1.0f/q1) * sr_inv), -32768.0f), 32767.0f) * scale_r;
        rq[2] = fminf(fmaxf(rintf((1.0f/q2) * sr_inv), -32768.0f), 32767.0f) * scale_r;
        rq[3] = fminf(fmaxf(rintf((1.0f/q3) * sr_inv), -32768.0f), 32767.0f) * scale_r;
    }

    const size_t base = ((size_t)(b * Jdim + jc * JCHUNK)) * Cdim + c0;
    #pragma unroll 4
    for (int r = 0; r < JCHUNK; ++r) {
        float xq0, xq1, xq2, xq3;
        if (UC) {
            const c4 q = *reinterpret_cast<const c4*>(codes + base + (size_t)r * Cdim);
            xq0 = (float)q[0]*s; xq1 = (float)q[1]*s; xq2 = (float)q[2]*s; xq3 = (float)q[3]*s;
        } else {
            const f4 v = *reinterpret_cast<const f4*>(x + base + (size_t)r * Cdim);
            xq0 = code8f(v[0], sinv)*s; xq1 = code8f(v[1], sinv)*s;
            xq2 = code8f(v[2], sinv)*s; xq3 = code8f(v[3], sinv)*s;
        }
        float e0 = eq_from(xq0, gm0, ssub_inv, ssub) * rq[0];
        float e1 = eq_from(xq1, gm1, ssub_inv, ssub) * rq[1];
        float e2 = eq_from(xq2, gm2, ssub_inv, ssub) * rq[2];
        float e3 = eq_from(xq3, gm3, ssub_inv, ssub) * rq[3];
        f4 o;
        o[0] = fminf(fmaxf(rintf(e0 * so_inv), -128.0f), 127.0f) * scale_out;
        o[1] = fminf(fmaxf(rintf(e1 * so_inv), -128.0f), 127.0f) * scale_out;
        o[2] = fminf(fmaxf(rintf(e2 * so_inv), -128.0f), 127.0f) * scale_out;
        o[3] = fminf(fmaxf(rintf(e3 * so_inv), -128.0f), 127.0f) * scale_out;
        __builtin_nontemporal_store(o, reinterpret_cast<f4*>(out + base + (size_t)r * Cdim));
    }
}

extern "C" void kernel_launch(void* const* d_in, const int* in_sizes, int n_in,
                              void* d_out, int out_size, void* d_ws, size_t ws_size,
                              hipStream_t stream) {
    const float* x     = (const float*)d_in[0];
    const float* scale = (const float*)d_in[1];
    float* out = (float*)d_out;

    // ---- preferred: fused cooperative kernel (256 blocks, 2 grid syncs) ----
    {
        float* wsf = (float*)d_ws;   // needs 768 floats
        const float* xa = x; const float* sa = scale; float* oa = out; float* wa = wsf;
        void* args[4] = {(void*)&xa, (void*)&sa, (void*)&oa, (void*)&wa};
        hipError_t err = hipLaunchCooperativeKernel((const void*)k_fused,
                                                    dim3(FGRID), dim3(FBLK),
                                                    args, 0, stream);
        if (err == hipSuccess) return;
    }

    // ---- fallback: proven round-3 5-kernel path ----
    const bool uc = ws_size >= CODES_BYTES + FB_BYTES + P_BYTES;
    signed char* codes = uc ? (signed char*)d_ws : nullptr;
    float* fbuf = uc ? (float*)((char*)d_ws + CODES_BYTES) : (float*)d_ws;
    signed char* pmax = (signed char*)((char*)fbuf + FB_BYTES);
    signed char* pmin = pmax + PSIZE;

    if (uc) {
        k_pass1<true ><<<Bdim * NJC, 256, 0, stream>>>(x, scale, fbuf, codes, pmax, pmin);
        k_reduce1<<<256, 256, 0, stream>>>(scale, fbuf, pmax, pmin);
        k_pass2<true ><<<Bdim * NJC, 256, 0, stream>>>(x, codes, scale, fbuf);
        k_reduce2<<<256, 256, 0, stream>>>(fbuf);
        k_pass3<true ><<<Bdim * NJC, 256, 0, stream>>>(x, codes, scale, fbuf, out);
    } else {
        k_pass1<false><<<Bdim * NJC, 256, 0, stream>>>(x, scale, fbuf, codes, pmax, pmin);
        k_reduce1<<<256, 256, 0, stream>>>(scale, fbuf, pmax, pmin);
        k_pass2<false><<<Bdim * NJC, 256, 0, stream>>>(x, codes, scale, fbuf);
        k_reduce2<<<256, 256, 0, stream>>>(fbuf);
        k_pass3<false><<<Bdim * NJC, 256, 0, stream>>>(x, codes, scale, fbuf, out);
    }
}

// Round 5
// 125.670 us; speedup vs baseline: 1.4988x; 1.4988x over previous
//
#include <hip/hip_runtime.h>
#include <hip/hip_cooperative_groups.h>
#include <math.h>

namespace cgx = cooperative_groups;

// Quantized softmax over axis 1 of x(8, 4096, 1024) fp32.
// Groups: g = (b, c) column, 8192 groups of 4096 elements (stride 1024 floats).
//
// FUSED single-kernel (cooperative, 256 blocks x 1024 thr = 1 block/CU):
//   Each block owns a (b, 32-column) slab = 32 full groups. The slab's int8
//   codes live in LDS (4096 x 32 B = 128 KiB; reg-resident version spilled —
//   round 4: VGPR capped at 64, ~165 MB scratch writes, 173 us).
//   Only 3 global scalars (amax_sub, max_s, min_s) cross blocks: per-block
//   values in ws + 2 grid syncs + per-block re-reduction (atomic-free).
// Traffic: read x once (134 MB, NT) + write out once (134 MB, NT) + ~3 KB.
// Arithmetic is op-for-op the round-4 path (absmax vs np ref was 0.0).

typedef float       f4 __attribute__((ext_vector_type(4)));
typedef signed char c4 __attribute__((ext_vector_type(4)));

static constexpr int Bdim = 8;
static constexpr int Jdim = 4096;
static constexpr int Cdim = 1024;

// ---- fused geometry ----
static constexpr int CT    = 32;            // columns per block
static constexpr int NCT   = Cdim / CT;     // 32
static constexpr int FGRID = Bdim * NCT;    // 256 blocks = 1 per CU
static constexpr int FBLK  = 1024;          // 16 waves
static constexpr int KROWS = 32;            // row-steps per thread
static constexpr int RSTEP = 128;           // row stride between steps

__device__ __forceinline__ float code8f(float x, float sinv) {
    // int8 code as float; rintf = round-half-even matches jnp.round
    return fminf(fmaxf(rintf(x * sinv), -128.0f), 127.0f);
}
// e_q = fq16(exp(fq16(clip(xq - gmax, -12, 0)))); scale_e = 1/32767 exactly
// (group-max element has sub==0 -> e==1 -> absmax(e)==1).
__device__ __forceinline__ float eq_from(float xq, float gmv, float ssub_inv, float ssub) {
    float sub = fminf(fmaxf(xq - gmv, -12.0f), 0.0f);
    float q   = rintf(sub * ssub_inv);
    float e   = __expf(q * ssub);
    return rintf(e * 32767.0f) * (1.0f / 32767.0f);
}

__device__ __forceinline__ f4 shfl_xor4(f4 v, int off) {
    f4 r; r[0] = __shfl_xor(v[0], off); r[1] = __shfl_xor(v[1], off);
    r[2] = __shfl_xor(v[2], off); r[3] = __shfl_xor(v[3], off); return r;
}
__device__ __forceinline__ f4 fmax4v(f4 a, f4 b) {
    f4 r; r[0]=fmaxf(a[0],b[0]); r[1]=fmaxf(a[1],b[1]);
    r[2]=fmaxf(a[2],b[2]); r[3]=fmaxf(a[3],b[3]); return r;
}
__device__ __forceinline__ f4 fmin4v(f4 a, f4 b) {
    f4 r; r[0]=fminf(a[0],b[0]); r[1]=fminf(a[1],b[1]);
    r[2]=fminf(a[2],b[2]); r[3]=fminf(a[3],b[3]); return r;
}
__device__ __forceinline__ f4 add4v(f4 a, f4 b) {
    f4 r; r[0]=a[0]+b[0]; r[1]=a[1]+b[1]; r[2]=a[2]+b[2]; r[3]=a[3]+b[3]; return r;
}

__global__ __launch_bounds__(FBLK, 4) void k_fused(const float* __restrict__ x,
                                                   const float* __restrict__ scale,
                                                   float* __restrict__ out,
                                                   float* __restrict__ wsf) {
    const int bid   = blockIdx.x;
    const int b     = bid / NCT;
    const int ctile = bid % NCT;
    const int t     = threadIdx.x;
    const int cgp   = t & 7;       // col group: 4 cols
    const int rg    = t >> 3;      // 0..127 row group
    const int w     = t >> 6;      // wave 0..15
    const int l     = t & 63;      // lane
    const float s    = scale[0];
    const float sinv = 1.0f / s;

    float* dblk  = wsf;            // [256] per-block max |clip(sub)|
    float* smaxb = wsf + 256;      // [256] per-block max group-sum
    float* sminb = wsf + 512;      // [256] per-block min group-sum

    __shared__ signed char lcode[Jdim][CT];   // 128 KiB: the block's code slab
    __shared__ f4 lA[16][8], lB[16][8];
    __shared__ f4 gmaxs[8];        // per-colgroup max codes (block scope)
    __shared__ f4 scol[8];         // per-colgroup group sums
    __shared__ float bc[3];

    const size_t base = ((size_t)b * Jdim + rg) * Cdim + (size_t)(ctile * CT + cgp * 4);
    signed char* lc = &lcode[rg][cgp * 4];

    // ---------- Phase A: read x (NT), quantize -> LDS, per-col max/min ----------
    f4 vmax = {-1e30f, -1e30f, -1e30f, -1e30f};
    f4 vmin = { 1e30f,  1e30f,  1e30f,  1e30f};
#pragma unroll
    for (int k = 0; k < KROWS; ++k) {
        const f4 v = __builtin_nontemporal_load(
            reinterpret_cast<const f4*>(x + base + (size_t)k * RSTEP * Cdim));
        f4 q;
        q[0] = code8f(v[0], sinv); q[1] = code8f(v[1], sinv);
        q[2] = code8f(v[2], sinv); q[3] = code8f(v[3], sinv);
        vmax = fmax4v(vmax, q); vmin = fmin4v(vmin, q);
        *reinterpret_cast<c4*>(lc + (size_t)k * RSTEP * CT) =
            (c4){(signed char)(int)q[0], (signed char)(int)q[1],
                 (signed char)(int)q[2], (signed char)(int)q[3]};
    }
    // intra-wave reduce over rg bits (lanes 8,16,32 apart share col group)
#pragma unroll
    for (int off = 8; off < 64; off <<= 1) {
        vmax = fmax4v(vmax, shfl_xor4(vmax, off));
        vmin = fmin4v(vmin, shfl_xor4(vmin, off));
    }
    if (l < 8) { lA[w][l] = vmax; lB[w][l] = vmin; }
    __syncthreads();
    if (w == 0) {
        const int wcg = l & 7, wi = l >> 3;         // wi 0..7
        f4 m = fmax4v(lA[wi][wcg], lA[wi + 8][wcg]);
        f4 n = fmin4v(lB[wi][wcg], lB[wi + 8][wcg]);
#pragma unroll
        for (int off = 8; off < 64; off <<= 1) {
            m = fmax4v(m, shfl_xor4(m, off));
            n = fmin4v(n, shfl_xor4(n, off));
        }
        if (l < 8) gmaxs[l] = m;                     // codes (as float)
        // d = max over 4 cols of min(12, gmax_v - gmin_v)  (same fp ops as ref)
        float d;
        {
            float d0 = fminf(12.0f, m[0]*s - n[0]*s);
            float d1 = fminf(12.0f, m[1]*s - n[1]*s);
            float d2 = fminf(12.0f, m[2]*s - n[2]*s);
            float d3 = fminf(12.0f, m[3]*s - n[3]*s);
            d = fmaxf(fmaxf(d0, d1), fmaxf(d2, d3));
        }
#pragma unroll
        for (int off = 1; off < 8; off <<= 1) d = fmaxf(d, __shfl_xor(d, off));
        if (l == 0) dblk[bid] = d;
    }
    cgx::this_grid().sync();

    // ---------- Phase B: amax_sub -> ssub; e_q sums per column ----------
    if (w == 0) {
        const f4 dv = *reinterpret_cast<const f4*>(dblk + 4 * l);  // 64 x 4 = 256
        float dm = fmaxf(fmaxf(dv[0], dv[1]), fmaxf(dv[2], dv[3]));
#pragma unroll
        for (int off = 1; off < 64; off <<= 1) dm = fmaxf(dm, __shfl_xor(dm, off));
        if (l == 0) bc[0] = dm;
    }
    __syncthreads();
    const float amax = fmaxf(bc[0], 1e-9f);
    const float ssub = amax / 32767.0f;
    const float ssub_inv = 1.0f / ssub;
    const f4 gmc = gmaxs[cgp];
    const f4 gm  = {gmc[0]*s, gmc[1]*s, gmc[2]*s, gmc[3]*s};

    f4 acc = {0.f, 0.f, 0.f, 0.f};
#pragma unroll
    for (int k = 0; k < KROWS; ++k) {
        const c4 q = *reinterpret_cast<const c4*>(lc + (size_t)k * RSTEP * CT);
        acc[0] += eq_from((float)q[0]*s, gm[0], ssub_inv, ssub);
        acc[1] += eq_from((float)q[1]*s, gm[1], ssub_inv, ssub);
        acc[2] += eq_from((float)q[2]*s, gm[2], ssub_inv, ssub);
        acc[3] += eq_from((float)q[3]*s, gm[3], ssub_inv, ssub);
    }
#pragma unroll
    for (int off = 8; off < 64; off <<= 1) acc = add4v(acc, shfl_xor4(acc, off));
    if (l < 8) lA[w][l] = acc;                       // reuse lA
    __syncthreads();
    if (w == 0) {
        const int wcg = l & 7, wi = l >> 3;
        f4 tsum = add4v(lA[wi][wcg], lA[wi + 8][wcg]);
#pragma unroll
        for (int off = 8; off < 64; off <<= 1) tsum = add4v(tsum, shfl_xor4(tsum, off));
        if (l < 8) scol[l] = tsum;
        float mx = fmaxf(fmaxf(tsum[0], tsum[1]), fmaxf(tsum[2], tsum[3]));
        float mn = fminf(fminf(tsum[0], tsum[1]), fminf(tsum[2], tsum[3]));
#pragma unroll
        for (int off = 1; off < 8; off <<= 1) {
            mx = fmaxf(mx, __shfl_xor(mx, off));
            mn = fminf(mn, __shfl_xor(mn, off));
        }
        if (l == 0) { smaxb[bid] = mx; sminb[bid] = mn; }
    }
    cgx::this_grid().sync();

    // ---------- Phase C: derive scales; out = fq8(e_q * r_q) ----------
    if (w == 0) {
        const f4 mv = *reinterpret_cast<const f4*>(smaxb + 4 * l);
        const f4 nv = *reinterpret_cast<const f4*>(sminb + 4 * l);
        float mx = fmaxf(fmaxf(mv[0], mv[1]), fmaxf(mv[2], mv[3]));
        float mn = fminf(fminf(nv[0], nv[1]), fminf(nv[2], nv[3]));
#pragma unroll
        for (int off = 1; off < 64; off <<= 1) {
            mx = fmaxf(mx, __shfl_xor(mx, off));
            mn = fminf(mn, __shfl_xor(mn, off));
        }
        if (l == 0) { bc[1] = mx; bc[2] = mn; }
    }
    __syncthreads();
    const float max_s = bc[1], min_s = bc[2];
    // fq monotone: min s_q = fq(min s); max r = 1/min s_q; max r_q = fq(max r)
    const float scale_s = fmaxf(max_s, 1e-9f) / 32767.0f;
    const float ss_inv  = 1.0f / scale_s;
    const float minsq   = fminf(fmaxf(rintf(min_s * ss_inv), -32768.0f), 32767.0f) * scale_s;
    const float maxr    = 1.0f / minsq;
    const float scale_r = fmaxf(maxr, 1e-9f) / 32767.0f;
    const float sr_inv  = 1.0f / scale_r;
    const float maxrq   = fminf(fmaxf(rintf(maxr * sr_inv), -32768.0f), 32767.0f) * scale_r;
    const float scale_out = fmaxf(maxrq, 1e-9f) / 127.0f;
    const float so_inv  = 1.0f / scale_out;

    const f4 sc = scol[cgp];
    f4 rq;
#pragma unroll
    for (int i = 0; i < 4; ++i) {
        float qv = fminf(fmaxf(rintf(sc[i] * ss_inv), -32768.0f), 32767.0f) * scale_s;
        rq[i] = fminf(fmaxf(rintf((1.0f / qv) * sr_inv), -32768.0f), 32767.0f) * scale_r;
    }

#pragma unroll
    for (int k = 0; k < KROWS; ++k) {
        const c4 q = *reinterpret_cast<const c4*>(lc + (size_t)k * RSTEP * CT);
        f4 o;
        {
            float e0 = eq_from((float)q[0]*s, gm[0], ssub_inv, ssub) * rq[0];
            float e1 = eq_from((float)q[1]*s, gm[1], ssub_inv, ssub) * rq[1];
            float e2 = eq_from((float)q[2]*s, gm[2], ssub_inv, ssub) * rq[2];
            float e3 = eq_from((float)q[3]*s, gm[3], ssub_inv, ssub) * rq[3];
            o[0] = fminf(fmaxf(rintf(e0 * so_inv), -128.0f), 127.0f) * scale_out;
            o[1] = fminf(fmaxf(rintf(e1 * so_inv), -128.0f), 127.0f) * scale_out;
            o[2] = fminf(fmaxf(rintf(e2 * so_inv), -128.0f), 127.0f) * scale_out;
            o[3] = fminf(fmaxf(rintf(e3 * so_inv), -128.0f), 127.0f) * scale_out;
        }
        __builtin_nontemporal_store(o,
            reinterpret_cast<f4*>(out + base + (size_t)k * RSTEP * Cdim));
    }
}

// ======================= round-3 fallback path =======================
static constexpr int JCHUNK = 16;
static constexpr int NJC = Jdim / JCHUNK;         // 256
static constexpr int NG = Bdim * Cdim;            // 8192
static constexpr int PSIZE = Bdim * NJC * Cdim;   // 2,097,152

static constexpr int SC_OFF   = 0;
static constexpr int GMAX_OFF = 16;
static constexpr int S_OFF    = GMAX_OFF + NG;
static constexpr int PS_OFF   = S_OFF + NG;
static constexpr size_t FB_BYTES    = ((size_t)PS_OFF + PSIZE) * 4;
static constexpr size_t CODES_BYTES = (size_t)Bdim * Jdim * Cdim;
static constexpr size_t P_BYTES     = 2 * (size_t)PSIZE;

template <bool WC>
__global__ __launch_bounds__(256) void k_pass1(const float* __restrict__ x,
                                               const float* __restrict__ scale,
                                               float* __restrict__ fbuf,
                                               signed char* __restrict__ codes,
                                               signed char* __restrict__ pmax,
                                               signed char* __restrict__ pmin) {
    if (blockIdx.x == 0 && threadIdx.x == 0) {
        fbuf[SC_OFF + 0] = 0.0f;
        fbuf[SC_OFF + 1] = 0.0f;
        fbuf[SC_OFF + 2] = __int_as_float(0x7f800000);
    }
    const int b  = blockIdx.x / NJC;
    const int jc = blockIdx.x % NJC;
    const int c0 = threadIdx.x * 4;
    const float sinv = 1.0f / scale[0];
    const size_t base = ((size_t)(b * Jdim + jc * JCHUNK)) * Cdim + c0;

    f4 vmax = {-1e30f, -1e30f, -1e30f, -1e30f};
    f4 vmin = { 1e30f,  1e30f,  1e30f,  1e30f};
    #pragma unroll 4
    for (int r = 0; r < JCHUNK; ++r) {
        const f4 v = __builtin_nontemporal_load(
            reinterpret_cast<const f4*>(x + base + (size_t)r * Cdim));
        f4 q;
        q[0] = code8f(v[0], sinv); q[1] = code8f(v[1], sinv);
        q[2] = code8f(v[2], sinv); q[3] = code8f(v[3], sinv);
        vmax = fmax4v(vmax, q); vmin = fmin4v(vmin, q);
        if (WC) {
            c4 pk = {(signed char)(int)q[0], (signed char)(int)q[1],
                     (signed char)(int)q[2], (signed char)(int)q[3]};
            *reinterpret_cast<c4*>(codes + base + (size_t)r * Cdim) = pk;
        }
    }
    const size_t pidx = ((size_t)(b * NJC + jc)) * Cdim + c0;
    c4 mx = {(signed char)(int)vmax[0], (signed char)(int)vmax[1],
             (signed char)(int)vmax[2], (signed char)(int)vmax[3]};
    c4 mn = {(signed char)(int)vmin[0], (signed char)(int)vmin[1],
             (signed char)(int)vmin[2], (signed char)(int)vmin[3]};
    *reinterpret_cast<c4*>(pmax + pidx) = mx;
    *reinterpret_cast<c4*>(pmin + pidx) = mn;
}

__global__ __launch_bounds__(256) void k_reduce1(const float* __restrict__ scale,
                                                 float* __restrict__ fbuf,
                                                 const signed char* __restrict__ pmax,
                                                 const signed char* __restrict__ pmin) {
    const int b   = blockIdx.x / 32;
    const int ct  = blockIdx.x % 32;
    const int ci  = threadIdx.x & 31;
    const int sub = threadIdx.x >> 5;
    const int c   = ct * 32 + ci;

    int mx = -128, mn = 127;
    for (int jc = sub; jc < NJC; jc += 8) {
        const size_t idx = ((size_t)(b * NJC + jc)) * Cdim + c;
        mx = max(mx, (int)pmax[idx]);
        mn = min(mn, (int)pmin[idx]);
    }
    __shared__ int smx[8][32], smn[8][32];
    smx[sub][ci] = mx; smn[sub][ci] = mn;
    __syncthreads();
    for (int off = 4; off; off >>= 1) {
        if (sub < off) {
            smx[sub][ci] = max(smx[sub][ci], smx[sub + off][ci]);
            smn[sub][ci] = min(smn[sub][ci], smn[sub + off][ci]);
        }
        __syncthreads();
    }
    __shared__ float sd[32];
    if (sub == 0) {
        const float s = scale[0];
        fbuf[GMAX_OFF + b * Cdim + c] = (float)smx[0][ci];
        sd[ci] = fminf(12.0f, (float)smx[0][ci] * s - (float)smn[0][ci] * s);
    }
    __syncthreads();
    if (threadIdx.x == 0) {
        float m = sd[0];
        #pragma unroll
        for (int i = 1; i < 32; ++i) m = fmaxf(m, sd[i]);
        atomicMax(reinterpret_cast<unsigned int*>(fbuf + SC_OFF + 0), __float_as_uint(m));
    }
}

template <bool UC>
__global__ __launch_bounds__(256) void k_pass2(const float* __restrict__ x,
                                               const signed char* __restrict__ codes,
                                               const float* __restrict__ scale,
                                               float* __restrict__ fbuf) {
    const int b  = blockIdx.x / NJC;
    const int jc = blockIdx.x % NJC;
    const int c0 = threadIdx.x * 4;
    const float s = scale[0];
    const float sinv = 1.0f / s;
    const float amax = fmaxf(fbuf[SC_OFF + 0], 1e-9f);
    const float ssub = amax / 32767.0f;
    const float ssub_inv = 1.0f / ssub;
    const f4 gmc = *reinterpret_cast<const f4*>(fbuf + GMAX_OFF + b * Cdim + c0);
    const float gm0 = gmc[0]*s, gm1 = gmc[1]*s, gm2 = gmc[2]*s, gm3 = gmc[3]*s;
    const size_t base = ((size_t)(b * Jdim + jc * JCHUNK)) * Cdim + c0;

    float a0 = 0.f, a1 = 0.f, a2 = 0.f, a3 = 0.f;
    #pragma unroll 4
    for (int r = 0; r < JCHUNK; ++r) {
        float xq0, xq1, xq2, xq3;
        if (UC) {
            const c4 q = *reinterpret_cast<const c4*>(codes + base + (size_t)r * Cdim);
            xq0 = (float)q[0]*s; xq1 = (float)q[1]*s; xq2 = (float)q[2]*s; xq3 = (float)q[3]*s;
        } else {
            const f4 v = *reinterpret_cast<const f4*>(x + base + (size_t)r * Cdim);
            xq0 = code8f(v[0], sinv)*s; xq1 = code8f(v[1], sinv)*s;
            xq2 = code8f(v[2], sinv)*s; xq3 = code8f(v[3], sinv)*s;
        }
        a0 += eq_from(xq0, gm0, ssub_inv, ssub);
        a1 += eq_from(xq1, gm1, ssub_inv, ssub);
        a2 += eq_from(xq2, gm2, ssub_inv, ssub);
        a3 += eq_from(xq3, gm3, ssub_inv, ssub);
    }
    f4 acc = {a0, a1, a2, a3};
    *reinterpret_cast<f4*>(fbuf + PS_OFF + ((size_t)(b * NJC + jc)) * Cdim + c0) = acc;
}

__global__ __launch_bounds__(256) void k_reduce2(float* __restrict__ fbuf) {
    const int b   = blockIdx.x / 32;
    const int ct  = blockIdx.x % 32;
    const int ci  = threadIdx.x & 31;
    const int sub = threadIdx.x >> 5;
    const int c   = ct * 32 + ci;

    float p = 0.0f;
    for (int jc = sub; jc < NJC; jc += 8)
        p += fbuf[PS_OFF + ((size_t)(b * NJC + jc)) * Cdim + c];
    __shared__ float sp[8][32];
    sp[sub][ci] = p;
    __syncthreads();
    for (int off = 4; off; off >>= 1) {
        if (sub < off) sp[sub][ci] += sp[sub + off][ci];
        __syncthreads();
    }
    __shared__ float smx[32], smn[32];
    if (sub == 0) {
        const float t = sp[0][ci];
        fbuf[S_OFF + b * Cdim + c] = t;
        smx[ci] = t; smn[ci] = t;
    }
    __syncthreads();
    if (threadIdx.x == 0) {
        float mx = smx[0], mn = smn[0];
        #pragma unroll
        for (int i = 1; i < 32; ++i) { mx = fmaxf(mx, smx[i]); mn = fminf(mn, smn[i]); }
        atomicMax(reinterpret_cast<unsigned int*>(fbuf + SC_OFF + 1), __float_as_uint(mx));
        atomicMin(reinterpret_cast<unsigned int*>(fbuf + SC_OFF + 2), __float_as_uint(mn));
    }
}

template <bool UC>
__global__ __launch_bounds__(256) void k_pass3(const float* __restrict__ x,
                                               const signed char* __restrict__ codes,
                                               const float* __restrict__ scale,
                                               const float* __restrict__ fbuf,
                                               float* __restrict__ out) {
    const int b  = blockIdx.x / NJC;
    const int jc = blockIdx.x % NJC;
    const int c0 = threadIdx.x * 4;
    const float s = scale[0];
    const float sinv = 1.0f / s;

    const float amax = fmaxf(fbuf[SC_OFF + 0], 1e-9f);
    const float ssub = amax / 32767.0f;
    const float ssub_inv = 1.0f / ssub;

    const float max_s = fbuf[SC_OFF + 1];
    const float min_s = fbuf[SC_OFF + 2];
    const float scale_s = fmaxf(max_s, 1e-9f) / 32767.0f;
    const float ss_inv = 1.0f / scale_s;
    const float minsq = fminf(fmaxf(rintf(min_s * ss_inv), -32768.0f), 32767.0f) * scale_s;
    const float maxr  = 1.0f / minsq;
    const float scale_r = fmaxf(maxr, 1e-9f) / 32767.0f;
    const float sr_inv  = 1.0f / scale_r;
    const float maxrq = fminf(fmaxf(rintf(maxr * sr_inv), -32768.0f), 32767.0f) * scale_r;
    const float scale_out = fmaxf(maxrq, 1e-9f) / 127.0f;
    const float so_inv = 1.0f / scale_out;

    const f4 gmc = *reinterpret_cast<const f4*>(fbuf + GMAX_OFF + b * Cdim + c0);
    const float gm0 = gmc[0]*s, gm1 = gmc[1]*s, gm2 = gmc[2]*s, gm3 = gmc[3]*s;
    const f4 s4 = *reinterpret_cast<const f4*>(fbuf + S_OFF + b * Cdim + c0);

    f4 rq;
    {
        float q0 = fminf(fmaxf(rintf(s4[0] * ss_inv), -32768.0f), 32767.0f) * scale_s;
        float q1 = fminf(fmaxf(rintf(s4[1] * ss_inv), -32768.0f), 32767.0f) * scale_s;
        float q2 = fminf(fmaxf(rintf(s4[2] * ss_inv), -32768.0f), 32767.0f) * scale_s;
        float q3 = fminf(fmaxf(rintf(s4[3] * ss_inv), -32768.0f), 32767.0f) * scale_s;
        rq[0] = fminf(fmaxf(rintf((1.0f/q0) * sr_inv), -32768.0f), 32767.0f) * scale_r;
        rq[1] = fminf(fmaxf(rintf((1.0f/q1) * sr_inv), -32768.0f), 32767.0f) * scale_r;
        rq[2] = fminf(fmaxf(rintf((1.0f/q2) * sr_inv), -32768.0f), 32767.0f) * scale_r;
        rq[3] = fminf(fmaxf(rintf((1.0f/q3) * sr_inv), -32768.0f), 32767.0f) * scale_r;
    }

    const size_t base = ((size_t)(b * Jdim + jc * JCHUNK)) * Cdim + c0;
    #pragma unroll 4
    for (int r = 0; r < JCHUNK; ++r) {
        float xq0, xq1, xq2, xq3;
        if (UC) {
            const c4 q = *reinterpret_cast<const c4*>(codes + base + (size_t)r * Cdim);
            xq0 = (float)q[0]*s; xq1 = (float)q[1]*s; xq2 = (float)q[2]*s; xq3 = (float)q[3]*s;
        } else {
            const f4 v = *reinterpret_cast<const f4*>(x + base + (size_t)r * Cdim);
            xq0 = code8f(v[0], sinv)*s; xq1 = code8f(v[1], sinv)*s;
            xq2 = code8f(v[2], sinv)*s; xq3 = code8f(v[3], sinv)*s;
        }
        float e0 = eq_from(xq0, gm0, ssub_inv, ssub) * rq[0];
        float e1 = eq_from(xq1, gm1, ssub_inv, ssub) * rq[1];
        float e2 = eq_from(xq2, gm2, ssub_inv, ssub) * rq[2];
        float e3 = eq_from(xq3, gm3, ssub_inv, ssub) * rq[3];
        f4 o;
        o[0] = fminf(fmaxf(rintf(e0 * so_inv), -128.0f), 127.0f) * scale_out;
        o[1] = fminf(fmaxf(rintf(e1 * so_inv), -128.0f), 127.0f) * scale_out;
        o[2] = fminf(fmaxf(rintf(e2 * so_inv), -128.0f), 127.0f) * scale_out;
        o[3] = fminf(fmaxf(rintf(e3 * so_inv), -128.0f), 127.0f) * scale_out;
        __builtin_nontemporal_store(o, reinterpret_cast<f4*>(out + base + (size_t)r * Cdim));
    }
}

extern "C" void kernel_launch(void* const* d_in, const int* in_sizes, int n_in,
                              void* d_out, int out_size, void* d_ws, size_t ws_size,
                              hipStream_t stream) {
    const float* x     = (const float*)d_in[0];
    const float* scale = (const float*)d_in[1];
    float* out = (float*)d_out;

    // ---- preferred: fused cooperative kernel (codes slab in LDS) ----
    {
        float* wsf = (float*)d_ws;   // needs 768 floats
        const float* xa = x; const float* sa = scale; float* oa = out; float* wa = wsf;
        void* args[4] = {(void*)&xa, (void*)&sa, (void*)&oa, (void*)&wa};
        hipError_t err = hipLaunchCooperativeKernel((const void*)k_fused,
                                                    dim3(FGRID), dim3(FBLK),
                                                    args, 0, stream);
        if (err == hipSuccess) return;
    }

    // ---- fallback: proven round-3 5-kernel path (101 us) ----
    const bool uc = ws_size >= CODES_BYTES + FB_BYTES + P_BYTES;
    signed char* codes = uc ? (signed char*)d_ws : nullptr;
    float* fbuf = uc ? (float*)((char*)d_ws + CODES_BYTES) : (float*)d_ws;
    signed char* pmax = (signed char*)((char*)fbuf + FB_BYTES);
    signed char* pmin = pmax + PSIZE;

    if (uc) {
        k_pass1<true ><<<Bdim * NJC, 256, 0, stream>>>(x, scale, fbuf, codes, pmax, pmin);
        k_reduce1<<<256, 256, 0, stream>>>(scale, fbuf, pmax, pmin);
        k_pass2<true ><<<Bdim * NJC, 256, 0, stream>>>(x, codes, scale, fbuf);
        k_reduce2<<<256, 256, 0, stream>>>(fbuf);
        k_pass3<true ><<<Bdim * NJC, 256, 0, stream>>>(x, codes, scale, fbuf, out);
    } else {
        k_pass1<false><<<Bdim * NJC, 256, 0, stream>>>(x, scale, fbuf, codes, pmax, pmin);
        k_reduce1<<<256, 256, 0, stream>>>(scale, fbuf, pmax, pmin);
        k_pass2<false><<<Bdim * NJC, 256, 0, stream>>>(x, codes, scale, fbuf);
        k_reduce2<<<256, 256, 0, stream>>>(fbuf);
        k_pass3<false><<<Bdim * NJC, 256, 0, stream>>>(x, codes, scale, fbuf, out);
    }
}